// Round 1
// baseline (3819.003 us; speedup 1.0000x reference)
//
#include <hip/hip_runtime.h>

#define B_  16
#define T_  128
#define E_  300
#define EP_ 320
#define H_  1024
#define G3_ 3072
#define V_  32000

typedef __attribute__((ext_vector_type(8))) short short8;
typedef __attribute__((ext_vector_type(4))) float floatx4;

// d_out offsets (elements, fp32): logits, style, content, mu_s, logvar_s, mu_c, logvar_c
#define OF_STYLE   65536000ull
#define OF_CONTENT 65537024ull
#define OF_MUS     65540096ull
#define OF_LVS     65541120ull
#define OF_MUC     65542144ull
#define OF_LVC     65545216ull

__device__ __forceinline__ unsigned short f2bf(float f) {
  union { float f; unsigned u; } v; v.f = f;
  return (unsigned short)((v.u + 0x7fffu + ((v.u >> 16) & 1u)) >> 16);  // RNE
}

__device__ __forceinline__ float wsum(float v) {
  #pragma unroll
  for (int m = 1; m < 64; m <<= 1) v += __shfl_xor(v, m, 64);
  return v;
}

__device__ __forceinline__ float dot4(const float4 a, const float4 b) {
  return a.x * b.x + a.y * b.y + a.z * b.z + a.w * b.w;
}

__device__ __forceinline__ short8 cvt8(const float4 a, const float4 b) {
  short8 r;
  r[0] = (short)f2bf(a.x); r[1] = (short)f2bf(a.y);
  r[2] = (short)f2bf(a.z); r[3] = (short)f2bf(a.w);
  r[4] = (short)f2bf(b.x); r[5] = (short)f2bf(b.y);
  r[6] = (short)f2bf(b.z); r[7] = (short)f2bf(b.w);
  return r;
}

// ---- Wih fp32 [3072][300] -> bf16 [3072][320] (zero-padded K) ----
__global__ void k_wih(const float* __restrict__ src, unsigned short* __restrict__ dst) {
  int idx = blockIdx.x * 256 + threadIdx.x;
  const int stride = gridDim.x * 256;
  for (; idx < G3_ * EP_; idx += stride) {
    int row = idx / EP_;
    int k = idx - row * EP_;
    dst[idx] = (k < E_) ? f2bf(src[row * E_ + k]) : (unsigned short)0;
  }
}

// ---- embedding gather + LayerNorm -> e2[T][B][320] bf16 and shifted dec_e2 ----
__global__ void k_embed(const int* __restrict__ x, const int* __restrict__ sos,
                        const float* __restrict__ emb, const float* __restrict__ g,
                        const float* __restrict__ bta,
                        unsigned short* __restrict__ e2, unsigned short* __restrict__ de2) {
  const int row = blockIdx.x * 4 + (threadIdx.x >> 6);
  const int lane = threadIdx.x & 63;
  if (row > 2048) return;
  int tok, t = 0, b = 0;
  if (row < 2048) { b = row >> 7; t = row & 127; tok = x[row]; }
  else tok = sos[0];
  const float* src = emb + (size_t)tok * E_;
  float v[5]; float s = 0.f;
  #pragma unroll
  for (int i = 0; i < 5; ++i) { int k = lane + i * 64; v[i] = (k < E_) ? src[k] : 0.f; s += v[i]; }
  s = wsum(s);
  const float mu = s * (1.f / (float)E_);
  float q = 0.f;
  #pragma unroll
  for (int i = 0; i < 5; ++i) { int k = lane + i * 64; if (k < E_) { float d = v[i] - mu; q += d * d; } }
  q = wsum(q);
  const float rstd = rsqrtf(q * (1.f / (float)E_) + 1e-5f);
  #pragma unroll
  for (int i = 0; i < 5; ++i) {
    int k = lane + i * 64;  // 0..319
    unsigned short us = (k < E_) ? f2bf((v[i] - mu) * rstd * g[k] + bta[k]) : (unsigned short)0;
    if (row < 2048) {
      e2[(size_t)(t * 16 + b) * EP_ + k] = us;
      if (t < T_ - 1) de2[(size_t)((t + 1) * 16 + b) * EP_ + k] = us;
    } else {
      for (int bb = 0; bb < 16; ++bb) de2[(size_t)bb * EP_ + k] = us;  // dec_in[:,0,:] = LN(emb[sos])
    }
  }
}

// ---- xg = e @ Wih^T + bih : M=3072(g) N=2048(t*16+b) K=320, out xg[T][3H][B] fp32 ----
__global__ __launch_bounds__(256) void k_xg(const unsigned short* __restrict__ A,
                                            const unsigned short* __restrict__ Bm,
                                            const float* __restrict__ bih,
                                            float* __restrict__ xg) {
  __shared__ unsigned short lA[128 * 40];  // rows padded 32->40 bf16: 2-way-free LDS banks
  __shared__ unsigned short lB[128 * 40];
  const int tid = threadIdx.x;
  const int lane = tid & 63, wave = tid >> 6;
  const int wm = wave >> 1, wn = wave & 1;
  const int m0 = (blockIdx.x >> 4) * 128, n0 = (blockIdx.x & 15) * 128;
  floatx4 acc[4][4];
  #pragma unroll
  for (int i = 0; i < 4; ++i)
    #pragma unroll
    for (int jj = 0; jj < 4; ++jj) acc[i][jj] = (floatx4){0.f, 0.f, 0.f, 0.f};
  for (int kt = 0; kt < 10; ++kt) {
    const int k0 = kt * 32;
    __syncthreads();
    #pragma unroll
    for (int gi = 0; gi < 2; ++gi) {
      int gidx = tid + gi * 256;
      int r = gidx >> 2, kc = gidx & 3;
      short8 va = *(const short8*)(A + (size_t)(m0 + r) * EP_ + k0 + kc * 8);
      *(short8*)(&lA[r * 40 + kc * 8]) = va;
      short8 vb = *(const short8*)(Bm + (size_t)(n0 + r) * EP_ + k0 + kc * 8);
      *(short8*)(&lB[r * 40 + kc * 8]) = vb;
    }
    __syncthreads();
    short8 aF[4], bF[4];
    #pragma unroll
    for (int ms = 0; ms < 4; ++ms)
      aF[ms] = *(const short8*)(&lA[(wm * 64 + ms * 16 + (lane & 15)) * 40 + ((lane >> 4) << 3)]);
    #pragma unroll
    for (int ns = 0; ns < 4; ++ns)
      bF[ns] = *(const short8*)(&lB[(wn * 64 + ns * 16 + (lane & 15)) * 40 + ((lane >> 4) << 3)]);
    #pragma unroll
    for (int ms = 0; ms < 4; ++ms)
      #pragma unroll
      for (int ns = 0; ns < 4; ++ns)
        acc[ms][ns] = __builtin_amdgcn_mfma_f32_16x16x32_bf16(aF[ms], bF[ns], acc[ms][ns], 0, 0, 0);
  }
  #pragma unroll
  for (int ms = 0; ms < 4; ++ms) {
    const int mg0 = m0 + wm * 64 + ms * 16 + ((lane >> 4) << 2);
    #pragma unroll
    for (int ns = 0; ns < 4; ++ns) {
      const int nn = n0 + wn * 64 + ns * 16 + (lane & 15);
      const int tt = nn >> 4, bb = nn & 15;
      #pragma unroll
      for (int r = 0; r < 4; ++r)
        xg[(size_t)tt * (G3_ * 16) + (size_t)(mg0 + r) * 16 + bb] = acc[ms][ns][r] + bih[mg0 + r];
    }
  }
}

// ---- logits = ys @ out_W^T + out_b : M=2048 N=32000 K=1024 (B converted fp32->bf16 inline) ----
__global__ __launch_bounds__(256) void k_final(const unsigned short* __restrict__ Ay,
                                               const float* __restrict__ Bw,
                                               const float* __restrict__ obias,
                                               float* __restrict__ out) {
  __shared__ unsigned short lA[128 * 40];
  __shared__ unsigned short lB[128 * 40];
  const int tid = threadIdx.x;
  const int lane = tid & 63, wave = tid >> 6;
  const int wm = wave >> 1, wn = wave & 1;
  const int m0 = (blockIdx.x & 15) * 128, n0 = (blockIdx.x >> 4) * 128;  // m-fast: 16 blocks share a B panel in L2
  floatx4 acc[4][4];
  #pragma unroll
  for (int i = 0; i < 4; ++i)
    #pragma unroll
    for (int jj = 0; jj < 4; ++jj) acc[i][jj] = (floatx4){0.f, 0.f, 0.f, 0.f};
  for (int kt = 0; kt < 32; ++kt) {
    const int k0 = kt * 32;
    __syncthreads();
    #pragma unroll
    for (int gi = 0; gi < 2; ++gi) {
      int gidx = tid + gi * 256;
      int r = gidx >> 2, kc = gidx & 3;
      short8 va = *(const short8*)(Ay + (size_t)(m0 + r) * H_ + k0 + kc * 8);
      *(short8*)(&lA[r * 40 + kc * 8]) = va;
    }
    #pragma unroll
    for (int gi = 0; gi < 4; ++gi) {
      int gidx = tid + gi * 256;
      int r = gidx >> 3, kc = gidx & 7;
      float4 f = *(const float4*)(Bw + (size_t)(n0 + r) * H_ + k0 + kc * 4);
      union { unsigned short us[4]; unsigned long long u; } pk;
      pk.us[0] = f2bf(f.x); pk.us[1] = f2bf(f.y); pk.us[2] = f2bf(f.z); pk.us[3] = f2bf(f.w);
      *(unsigned long long*)(&lB[r * 40 + kc * 4]) = pk.u;
    }
    __syncthreads();
    short8 aF[4], bF[4];
    #pragma unroll
    for (int ms = 0; ms < 4; ++ms)
      aF[ms] = *(const short8*)(&lA[(wm * 64 + ms * 16 + (lane & 15)) * 40 + ((lane >> 4) << 3)]);
    #pragma unroll
    for (int ns = 0; ns < 4; ++ns)
      bF[ns] = *(const short8*)(&lB[(wn * 64 + ns * 16 + (lane & 15)) * 40 + ((lane >> 4) << 3)]);
    #pragma unroll
    for (int ms = 0; ms < 4; ++ms)
      #pragma unroll
      for (int ns = 0; ns < 4; ++ns)
        acc[ms][ns] = __builtin_amdgcn_mfma_f32_16x16x32_bf16(aF[ms], bF[ns], acc[ms][ns], 0, 0, 0);
  }
  #pragma unroll
  for (int ns = 0; ns < 4; ++ns) {
    const int nn = n0 + wn * 64 + ns * 16 + (lane & 15);
    const float bs = obias[nn];
    #pragma unroll
    for (int ms = 0; ms < 4; ++ms) {
      const int mm = m0 + wm * 64 + ms * 16 + ((lane >> 4) << 2);
      #pragma unroll
      for (int r = 0; r < 4; ++r)
        out[(size_t)(mm + r) * V_ + nn] = acc[ms][ns][r] + bs;
    }
  }
}

// ---- GRU recurrence: 64-WG gang, WG j owns h cols [j*16, j*16+16). Whh B-frags live in VGPRs.
// h broadcast via LLC (device-scope atomics) + flag barrier. fp32 master state in registers. ----
__global__ __launch_bounds__(256, 1) void k_gru(const float* __restrict__ xg,
                                                const float* __restrict__ Whh,
                                                const float* __restrict__ bhh,
                                                const float* __restrict__ h0,
                                                unsigned* hbuf, int* flags,
                                                float* __restrict__ hn_out,
                                                unsigned short* __restrict__ ys) {
  __shared__ unsigned short lh[16 * 1032];   // h staging, row pad 1024->1032 (2-way-free banks)
  __shared__ float lred[3072];               // [wave][tau][n][m] partial tiles
  __shared__ unsigned short lpack[256];
  const int tid = threadIdx.x;
  const int lane = tid & 63, wave = tid >> 6;
  const int j = blockIdx.x;
  const int b = tid & 15, c = tid >> 4;
  const int hc = j * 16 + c;
  const int kbase = wave * 256;  // each wave covers a K-quarter

  // Load Whh B-fragments (fp32 -> bf16) into registers, once.
  short8 bfrag[3][8];
  #pragma unroll
  for (int tau = 0; tau < 3; ++tau) {
    const float* wr = Whh + (size_t)(tau * H_ + j * 16 + (lane & 15)) * H_;
    #pragma unroll
    for (int s8 = 0; s8 < 8; ++s8) {
      int k = kbase + s8 * 32 + ((lane >> 4) << 3);
      float4 p0 = *(const float4*)(wr + k);
      float4 p1 = *(const float4*)(wr + k + 4);
      bfrag[tau][s8] = cvt8(p0, p1);
    }
  }
  const float bh0 = bhh[hc], bh1 = bhh[H_ + hc], bh2 = bhh[2 * H_ + hc];
  float h_own = h0 ? h0[b * H_ + hc] : 0.f;

  // Prologue: broadcast h_0 slice into hbuf[0], then gang barrier.
  lpack[b * 16 + c] = f2bf(h_own);
  __syncthreads();
  if (tid < 128) {
    int b2 = tid >> 3, cp = tid & 7;
    unsigned lo = lpack[b2 * 16 + cp * 2];
    unsigned hi = lpack[b2 * 16 + cp * 2 + 1];
    __hip_atomic_store(hbuf + b2 * 512 + j * 8 + cp, lo | (hi << 16),
                       __ATOMIC_RELAXED, __HIP_MEMORY_SCOPE_AGENT);
  }
  __threadfence();
  __syncthreads();
  if (tid == 0) __hip_atomic_store(flags + j, 1, __ATOMIC_RELEASE, __HIP_MEMORY_SCOPE_AGENT);
  if (wave == 0) {
    for (;;) {
      int f = __hip_atomic_load(flags + lane, __ATOMIC_RELAXED, __HIP_MEMORY_SCOPE_AGENT);
      if (__all(f >= 1)) break;   // poison 0xAAAAAAAA is negative -> safe
      __builtin_amdgcn_s_sleep(1);
    }
  }
  __syncthreads();

  for (int s = 0; s < T_; ++s) {
    // Stage full h_s (bf16, 32KB) from LLC into LDS; atomic loads bypass stale per-XCD L2.
    {
      unsigned long long* src = (unsigned long long*)(hbuf + (s & 1) * 8192);
      #pragma unroll
      for (int i = 0; i < 16; ++i) {
        int qi = tid + i * 256;  // row i, 8B col 8*tid
        unsigned long long v = __hip_atomic_load(src + qi, __ATOMIC_RELAXED, __HIP_MEMORY_SCOPE_AGENT);
        *(unsigned long long*)(&lh[i * 1032 + (qi & 255) * 4]) = v;
      }
    }
    __syncthreads();
    floatx4 a0 = {0.f,0.f,0.f,0.f}, a1 = {0.f,0.f,0.f,0.f}, a2 = {0.f,0.f,0.f,0.f};
    #pragma unroll
    for (int s8 = 0; s8 < 8; ++s8) {
      short8 aF = *(const short8*)(&lh[(lane & 15) * 1032 + kbase + s8 * 32 + ((lane >> 4) << 3)]);
      a0 = __builtin_amdgcn_mfma_f32_16x16x32_bf16(aF, bfrag[0][s8], a0, 0, 0, 0);
      a1 = __builtin_amdgcn_mfma_f32_16x16x32_bf16(aF, bfrag[1][s8], a1, 0, 0, 0);
      a2 = __builtin_amdgcn_mfma_f32_16x16x32_bf16(aF, bfrag[2][s8], a2, 0, 0, 0);
    }
    {
      int pb = wave * 768 + (lane & 15) * 16 + ((lane >> 4) << 2);
      *(floatx4*)(&lred[pb])       = a0;
      *(floatx4*)(&lred[pb + 256]) = a1;
      *(floatx4*)(&lred[pb + 512]) = a2;
    }
    __syncthreads();
    float g0 = bh0, g1 = bh1, g2 = bh2;
    #pragma unroll
    for (int wv = 0; wv < 4; ++wv) {
      int rb = wv * 768 + c * 16 + b;
      g0 += lred[rb]; g1 += lred[rb + 256]; g2 += lred[rb + 512];
    }
    const float* xgs = xg + (size_t)s * (G3_ * 16);
    const float xr = xgs[hc * 16 + b];
    const float xz = xgs[(H_ + hc) * 16 + b];
    const float xn = xgs[(2 * H_ + hc) * 16 + b];
    const float rg = 1.f / (1.f + expf(-(xr + g0)));
    const float zg = 1.f / (1.f + expf(-(xz + g1)));
    const float ng = tanhf(xn + rg * g2);
    const float hnew = (1.f - zg) * ng + zg * h_own;
    h_own = hnew;
    if (ys) ys[(size_t)(b * T_ + s) * H_ + hc] = f2bf(hnew);
    lpack[b * 16 + c] = f2bf(hnew);
    __syncthreads();
    if (tid < 128) {
      int b2 = tid >> 3, cp = tid & 7;
      unsigned lo = lpack[b2 * 16 + cp * 2];
      unsigned hi = lpack[b2 * 16 + cp * 2 + 1];
      __hip_atomic_store(hbuf + ((s + 1) & 1) * 8192 + b2 * 512 + j * 8 + cp,
                         lo | (hi << 16), __ATOMIC_RELAXED, __HIP_MEMORY_SCOPE_AGENT);
    }
    if (s < T_ - 1) {
      __threadfence();
      __syncthreads();
      if (tid == 0) __hip_atomic_store(flags + j, s + 2, __ATOMIC_RELEASE, __HIP_MEMORY_SCOPE_AGENT);
      if (wave == 0) {
        for (;;) {
          int f = __hip_atomic_load(flags + lane, __ATOMIC_RELAXED, __HIP_MEMORY_SCOPE_AGENT);
          if (__all(f >= s + 2)) break;
          __builtin_amdgcn_s_sleep(1);
        }
      }
      __syncthreads();
    }
  }
  if (hn_out) hn_out[b * H_ + hc] = h_own;
}

// ---- VAE heads: mu/logvar/style/content (+ cat buffer for fc). One wave per (b,o). ----
__global__ void k_heads(const float* __restrict__ hn,
                        const float* __restrict__ musW, const float* __restrict__ musb,
                        const float* __restrict__ varsW, const float* __restrict__ varsb,
                        const float* __restrict__ mucW, const float* __restrict__ mucb,
                        const float* __restrict__ varcW, const float* __restrict__ varcb,
                        const float* __restrict__ eps_s, const float* __restrict__ eps_c,
                        float* __restrict__ out, float* __restrict__ cat) {
  const int wv = blockIdx.x * 4 + (threadIdx.x >> 6);
  const int lane = threadIdx.x & 63;
  const int b = wv >> 8, o = wv & 255;
  const float* h = hn + (size_t)b * H_;
  const float *w1, *w2; float bb1, bb2, ep; int oc = 0;
  const int smode = (o < 64);
  if (smode) { w1 = musW + (size_t)o * H_;  w2 = varsW + (size_t)o * H_;  bb1 = musb[o];  bb2 = varsb[o];  ep = eps_s[b * 64 + o]; }
  else { oc = o - 64; w1 = mucW + (size_t)oc * H_; w2 = varcW + (size_t)oc * H_; bb1 = mucb[oc]; bb2 = varcb[oc]; ep = eps_c[b * 192 + oc]; }
  float s1 = 0.f, s2 = 0.f;
  #pragma unroll
  for (int i = 0; i < 4; ++i) {
    int k = lane * 4 + i * 256;
    float4 hv = *(const float4*)(h + k);
    float4 av = *(const float4*)(w1 + k);
    float4 bv = *(const float4*)(w2 + k);
    s1 += dot4(hv, av); s2 += dot4(hv, bv);
  }
  s1 = wsum(s1); s2 = wsum(s2);
  if (lane == 0) {
    const float mu = s1 + bb1, lv = s2 + bb2;
    const float sc = mu + ep * expf(0.5f * lv);
    if (smode) {
      out[OF_MUS + b * 64 + o] = mu;
      out[OF_LVS + b * 64 + o] = lv;
      out[OF_STYLE + b * 64 + o] = sc;
      cat[b * 256 + o] = sc;
    } else {
      out[OF_MUC + b * 192 + oc] = mu;
      out[OF_LVC + b * 192 + oc] = lv;
      out[OF_CONTENT + b * 192 + oc] = sc;
      cat[b * 256 + 64 + oc] = sc;
    }
  }
}

// ---- z = cat @ fc_W^T + fc_b : one wave per (b,h), K=256 = 64 lanes x float4 ----
__global__ void k_z(const float* __restrict__ cat, const float* __restrict__ fcW,
                    const float* __restrict__ fcb, float* __restrict__ z) {
  const int wv = blockIdx.x * 4 + (threadIdx.x >> 6);
  const int lane = threadIdx.x & 63;
  const int b = wv >> 10, h = wv & 1023;
  float4 a = *(const float4*)(cat + b * 256 + lane * 4);
  float4 w = *(const float4*)(fcW + (size_t)h * 256 + lane * 4);
  float p = dot4(a, w);
  p = wsum(p);
  if (lane == 0) z[b * H_ + h] = p + fcb[h];
}

extern "C" void kernel_launch(void* const* d_in, const int* in_sizes, int n_in,
                              void* d_out, int out_size, void* d_ws, size_t ws_size,
                              hipStream_t stream) {
  (void)in_sizes; (void)n_in; (void)out_size; (void)ws_size;
  const int*   x       = (const int*)d_in[0];
  const int*   sos     = (const int*)d_in[1];
  const float* eps_s   = (const float*)d_in[2];
  const float* eps_c   = (const float*)d_in[3];
  const float* emb     = (const float*)d_in[4];
  const float* ln_g    = (const float*)d_in[5];
  const float* ln_b    = (const float*)d_in[6];
  const float* enc_Wih = (const float*)d_in[7];
  const float* enc_Whh = (const float*)d_in[8];
  const float* enc_bih = (const float*)d_in[9];
  const float* enc_bhh = (const float*)d_in[10];
  const float* mus_W   = (const float*)d_in[11];
  const float* mus_b   = (const float*)d_in[12];
  const float* vars_W  = (const float*)d_in[13];
  const float* vars_b  = (const float*)d_in[14];
  const float* muc_W   = (const float*)d_in[15];
  const float* muc_b   = (const float*)d_in[16];
  const float* varc_W  = (const float*)d_in[17];
  const float* varc_b  = (const float*)d_in[18];
  const float* fc_W    = (const float*)d_in[19];
  const float* fc_b    = (const float*)d_in[20];
  const float* dec_Wih = (const float*)d_in[21];
  const float* dec_Whh = (const float*)d_in[22];
  const float* dec_bih = (const float*)d_in[23];
  const float* dec_bhh = (const float*)d_in[24];
  const float* out_W   = (const float*)d_in[25];
  const float* out_b   = (const float*)d_in[26];
  float* out = (float*)d_out;

  char* w = (char*)d_ws;   // ~58.5 MB total
  unsigned short* e2   = (unsigned short*)(w + 0);          // 1,310,720
  unsigned short* de2  = (unsigned short*)(w + 1310720);    // 1,310,720
  unsigned short* wihE = (unsigned short*)(w + 2621440);    // 1,966,080
  unsigned short* wihD = (unsigned short*)(w + 4587520);    // 1,966,080
  float* xgE           = (float*)(w + 6553600);             // 25,165,824
  float* xgD           = (float*)(w + 31719424);            // 25,165,824
  unsigned short* ys   = (unsigned short*)(w + 56885248);   // 4,194,304
  unsigned* hbuf       = (unsigned*)(w + 61079552);         // 65,536
  float* hn            = (float*)(w + 61145088);            // 65,536
  float* zb            = (float*)(w + 61210624);            // 65,536
  float* catb          = (float*)(w + 61276160);            // 16,384
  int* flagsE          = (int*)(w + 61292544);              // 256
  int* flagsD          = flagsE + 64;

  k_wih<<<960, 256, 0, stream>>>(enc_Wih, wihE);
  k_wih<<<960, 256, 0, stream>>>(dec_Wih, wihD);
  k_embed<<<513, 256, 0, stream>>>(x, sos, emb, ln_g, ln_b, e2, de2);
  k_xg<<<384, 256, 0, stream>>>(wihE, e2, enc_bih, xgE);
  k_xg<<<384, 256, 0, stream>>>(wihD, de2, dec_bih, xgD);
  k_gru<<<64, 256, 0, stream>>>(xgE, enc_Whh, enc_bhh, (const float*)nullptr,
                                hbuf, flagsE, hn, (unsigned short*)nullptr);
  k_heads<<<1024, 256, 0, stream>>>(hn, mus_W, mus_b, vars_W, vars_b,
                                    muc_W, muc_b, varc_W, varc_b, eps_s, eps_c, out, catb);
  k_z<<<4096, 256, 0, stream>>>(catb, fc_W, fc_b, zb);
  k_gru<<<64, 256, 0, stream>>>(xgD, dec_Whh, dec_bhh, zb,
                                hbuf, flagsD, (float*)nullptr, ys);
  k_final<<<4000, 256, 0, stream>>>(ys, out_W, out_b, out);
}

// Round 2
// 1739.321 us; speedup vs baseline: 2.1957x; 2.1957x over previous
//
#include <hip/hip_runtime.h>

#define B_  16
#define T_  128
#define E_  300
#define EP_ 320
#define H_  1024
#define G3_ 3072
#define V_  32000

typedef __attribute__((ext_vector_type(8))) short short8;
typedef __attribute__((ext_vector_type(4))) float floatx4;

// d_out offsets (elements, fp32): logits, style, content, mu_s, logvar_s, mu_c, logvar_c
#define OF_STYLE   65536000ull
#define OF_CONTENT 65537024ull
#define OF_MUS     65540096ull
#define OF_LVS     65541120ull
#define OF_MUC     65542144ull
#define OF_LVC     65545216ull

__device__ __forceinline__ unsigned short f2bf(float f) {
  union { float f; unsigned u; } v; v.f = f;
  return (unsigned short)((v.u + 0x7fffu + ((v.u >> 16) & 1u)) >> 16);  // RNE
}

__device__ __forceinline__ float wsum(float v) {
  #pragma unroll
  for (int m = 1; m < 64; m <<= 1) v += __shfl_xor(v, m, 64);
  return v;
}

__device__ __forceinline__ float dot4(const float4 a, const float4 b) {
  return a.x * b.x + a.y * b.y + a.z * b.z + a.w * b.w;
}

__device__ __forceinline__ short8 cvt8(const float4 a, const float4 b) {
  short8 r;
  r[0] = (short)f2bf(a.x); r[1] = (short)f2bf(a.y);
  r[2] = (short)f2bf(a.z); r[3] = (short)f2bf(a.w);
  r[4] = (short)f2bf(b.x); r[5] = (short)f2bf(b.y);
  r[6] = (short)f2bf(b.z); r[7] = (short)f2bf(b.w);
  return r;
}

// ---- Wih fp32 [3072][300] -> bf16 [3072][320] (zero-padded K) ----
__global__ void k_wih(const float* __restrict__ src, unsigned short* __restrict__ dst) {
  int idx = blockIdx.x * 256 + threadIdx.x;
  const int stride = gridDim.x * 256;
  for (; idx < G3_ * EP_; idx += stride) {
    int row = idx / EP_;
    int k = idx - row * EP_;
    dst[idx] = (k < E_) ? f2bf(src[row * E_ + k]) : (unsigned short)0;
  }
}

// ---- out_W fp32 [32000][1024] -> bf16 same layout (only when ws_size permits) ----
__global__ void k_cvtw(const float* __restrict__ src, unsigned short* __restrict__ dst, int n4) {
  int i = blockIdx.x * 256 + threadIdx.x;
  const int stride = gridDim.x * 256;
  for (; i < n4; i += stride) {
    float4 f = ((const float4*)src)[i];
    union { unsigned short us[4]; unsigned long long u; } pk;
    pk.us[0] = f2bf(f.x); pk.us[1] = f2bf(f.y); pk.us[2] = f2bf(f.z); pk.us[3] = f2bf(f.w);
    ((unsigned long long*)dst)[i] = pk.u;
  }
}

// ---- embedding gather + LayerNorm -> e2[T][B][320] bf16 and shifted dec_e2 ----
__global__ void k_embed(const int* __restrict__ x, const int* __restrict__ sos,
                        const float* __restrict__ emb, const float* __restrict__ g,
                        const float* __restrict__ bta,
                        unsigned short* __restrict__ e2, unsigned short* __restrict__ de2) {
  const int row = blockIdx.x * 4 + (threadIdx.x >> 6);
  const int lane = threadIdx.x & 63;
  if (row > 2048) return;
  int tok, t = 0, b = 0;
  if (row < 2048) { b = row >> 7; t = row & 127; tok = x[row]; }
  else tok = sos[0];
  const float* src = emb + (size_t)tok * E_;
  float v[5]; float s = 0.f;
  #pragma unroll
  for (int i = 0; i < 5; ++i) { int k = lane + i * 64; v[i] = (k < E_) ? src[k] : 0.f; s += v[i]; }
  s = wsum(s);
  const float mu = s * (1.f / (float)E_);
  float q = 0.f;
  #pragma unroll
  for (int i = 0; i < 5; ++i) { int k = lane + i * 64; if (k < E_) { float d = v[i] - mu; q += d * d; } }
  q = wsum(q);
  const float rstd = rsqrtf(q * (1.f / (float)E_) + 1e-5f);
  #pragma unroll
  for (int i = 0; i < 5; ++i) {
    int k = lane + i * 64;  // 0..319
    unsigned short us = (k < E_) ? f2bf((v[i] - mu) * rstd * g[k] + bta[k]) : (unsigned short)0;
    if (row < 2048) {
      e2[(size_t)(t * 16 + b) * EP_ + k] = us;
      if (t < T_ - 1) de2[(size_t)((t + 1) * 16 + b) * EP_ + k] = us;
    } else {
      for (int bb = 0; bb < 16; ++bb) de2[(size_t)bb * EP_ + k] = us;  // dec_in[:,0,:] = LN(emb[sos])
    }
  }
}

// ---- xg = e @ Wih^T + bih : M=3072(g) N=2048(t*16+b) K=320, out xg[T][3H][B] fp32 ----
__global__ __launch_bounds__(256) void k_xg(const unsigned short* __restrict__ A,
                                            const unsigned short* __restrict__ Bm,
                                            const float* __restrict__ bih,
                                            float* __restrict__ xg) {
  __shared__ unsigned short lA[128 * 40];  // rows padded 32->40 bf16: 2-way-free LDS banks
  __shared__ unsigned short lB[128 * 40];
  const int tid = threadIdx.x;
  const int lane = tid & 63, wave = tid >> 6;
  const int wm = wave >> 1, wn = wave & 1;
  const int m0 = (blockIdx.x >> 4) * 128, n0 = (blockIdx.x & 15) * 128;
  floatx4 acc[4][4];
  #pragma unroll
  for (int i = 0; i < 4; ++i)
    #pragma unroll
    for (int jj = 0; jj < 4; ++jj) acc[i][jj] = (floatx4){0.f, 0.f, 0.f, 0.f};
  for (int kt = 0; kt < 10; ++kt) {
    const int k0 = kt * 32;
    __syncthreads();
    #pragma unroll
    for (int gi = 0; gi < 2; ++gi) {
      int gidx = tid + gi * 256;
      int r = gidx >> 2, kc = gidx & 3;
      short8 va = *(const short8*)(A + (size_t)(m0 + r) * EP_ + k0 + kc * 8);
      *(short8*)(&lA[r * 40 + kc * 8]) = va;
      short8 vb = *(const short8*)(Bm + (size_t)(n0 + r) * EP_ + k0 + kc * 8);
      *(short8*)(&lB[r * 40 + kc * 8]) = vb;
    }
    __syncthreads();
    short8 aF[4], bF[4];
    #pragma unroll
    for (int ms = 0; ms < 4; ++ms)
      aF[ms] = *(const short8*)(&lA[(wm * 64 + ms * 16 + (lane & 15)) * 40 + ((lane >> 4) << 3)]);
    #pragma unroll
    for (int ns = 0; ns < 4; ++ns)
      bF[ns] = *(const short8*)(&lB[(wn * 64 + ns * 16 + (lane & 15)) * 40 + ((lane >> 4) << 3)]);
    #pragma unroll
    for (int ms = 0; ms < 4; ++ms)
      #pragma unroll
      for (int ns = 0; ns < 4; ++ns)
        acc[ms][ns] = __builtin_amdgcn_mfma_f32_16x16x32_bf16(aF[ms], bF[ns], acc[ms][ns], 0, 0, 0);
  }
  #pragma unroll
  for (int ms = 0; ms < 4; ++ms) {
    const int mg0 = m0 + wm * 64 + ms * 16 + ((lane >> 4) << 2);
    #pragma unroll
    for (int ns = 0; ns < 4; ++ns) {
      const int nn = n0 + wn * 64 + ns * 16 + (lane & 15);
      const int tt = nn >> 4, bb = nn & 15;
      #pragma unroll
      for (int r = 0; r < 4; ++r)
        xg[(size_t)tt * (G3_ * 16) + (size_t)(mg0 + r) * 16 + bb] = acc[ms][ns][r] + bih[mg0 + r];
    }
  }
}

// ---- logits GEMM, fp32-B fallback (B converted fp32->bf16 inline) ----
__global__ __launch_bounds__(256) void k_final(const unsigned short* __restrict__ Ay,
                                               const float* __restrict__ Bw,
                                               const float* __restrict__ obias,
                                               float* __restrict__ out) {
  __shared__ unsigned short lA[128 * 40];
  __shared__ unsigned short lB[128 * 40];
  const int tid = threadIdx.x;
  const int lane = tid & 63, wave = tid >> 6;
  const int wm = wave >> 1, wn = wave & 1;
  const int m0 = (blockIdx.x & 15) * 128, n0 = (blockIdx.x >> 4) * 128;
  floatx4 acc[4][4];
  #pragma unroll
  for (int i = 0; i < 4; ++i)
    #pragma unroll
    for (int jj = 0; jj < 4; ++jj) acc[i][jj] = (floatx4){0.f, 0.f, 0.f, 0.f};
  for (int kt = 0; kt < 32; ++kt) {
    const int k0 = kt * 32;
    __syncthreads();
    #pragma unroll
    for (int gi = 0; gi < 2; ++gi) {
      int gidx = tid + gi * 256;
      int r = gidx >> 2, kc = gidx & 3;
      short8 va = *(const short8*)(Ay + (size_t)(m0 + r) * H_ + k0 + kc * 8);
      *(short8*)(&lA[r * 40 + kc * 8]) = va;
    }
    #pragma unroll
    for (int gi = 0; gi < 4; ++gi) {
      int gidx = tid + gi * 256;
      int r = gidx >> 3, kc = gidx & 7;
      float4 f = *(const float4*)(Bw + (size_t)(n0 + r) * H_ + k0 + kc * 4);
      union { unsigned short us[4]; unsigned long long u; } pk;
      pk.us[0] = f2bf(f.x); pk.us[1] = f2bf(f.y); pk.us[2] = f2bf(f.z); pk.us[3] = f2bf(f.w);
      *(unsigned long long*)(&lB[r * 40 + kc * 4]) = pk.u;
    }
    __syncthreads();
    short8 aF[4], bF[4];
    #pragma unroll
    for (int ms = 0; ms < 4; ++ms)
      aF[ms] = *(const short8*)(&lA[(wm * 64 + ms * 16 + (lane & 15)) * 40 + ((lane >> 4) << 3)]);
    #pragma unroll
    for (int ns = 0; ns < 4; ++ns)
      bF[ns] = *(const short8*)(&lB[(wn * 64 + ns * 16 + (lane & 15)) * 40 + ((lane >> 4) << 3)]);
    #pragma unroll
    for (int ms = 0; ms < 4; ++ms)
      #pragma unroll
      for (int ns = 0; ns < 4; ++ns)
        acc[ms][ns] = __builtin_amdgcn_mfma_f32_16x16x32_bf16(aF[ms], bF[ns], acc[ms][ns], 0, 0, 0);
  }
  #pragma unroll
  for (int ns = 0; ns < 4; ++ns) {
    const int nn = n0 + wn * 64 + ns * 16 + (lane & 15);
    const float bs = obias[nn];
    #pragma unroll
    for (int ms = 0; ms < 4; ++ms) {
      const int mm = m0 + wm * 64 + ms * 16 + ((lane >> 4) << 2);
      #pragma unroll
      for (int r = 0; r < 4; ++r)
        out[(size_t)(mm + r) * V_ + nn] = acc[ms][ns][r] + bs;
    }
  }
}

// ---- logits GEMM, pre-converted bf16 B ----
__global__ __launch_bounds__(256) void k_final_bf(const unsigned short* __restrict__ Ay,
                                                  const unsigned short* __restrict__ Bw,
                                                  const float* __restrict__ obias,
                                                  float* __restrict__ out) {
  __shared__ unsigned short lA[128 * 40];
  __shared__ unsigned short lB[128 * 40];
  const int tid = threadIdx.x;
  const int lane = tid & 63, wave = tid >> 6;
  const int wm = wave >> 1, wn = wave & 1;
  const int m0 = (blockIdx.x & 15) * 128, n0 = (blockIdx.x >> 4) * 128;  // m-fast: 16 blocks share B panel in L2
  floatx4 acc[4][4];
  #pragma unroll
  for (int i = 0; i < 4; ++i)
    #pragma unroll
    for (int jj = 0; jj < 4; ++jj) acc[i][jj] = (floatx4){0.f, 0.f, 0.f, 0.f};
  for (int kt = 0; kt < 32; ++kt) {
    const int k0 = kt * 32;
    __syncthreads();
    #pragma unroll
    for (int gi = 0; gi < 2; ++gi) {
      int gidx = tid + gi * 256;
      int r = gidx >> 2, kc = gidx & 3;
      short8 va = *(const short8*)(Ay + (size_t)(m0 + r) * H_ + k0 + kc * 8);
      *(short8*)(&lA[r * 40 + kc * 8]) = va;
      short8 vb = *(const short8*)(Bw + (size_t)(n0 + r) * H_ + k0 + kc * 8);
      *(short8*)(&lB[r * 40 + kc * 8]) = vb;
    }
    __syncthreads();
    short8 aF[4], bF[4];
    #pragma unroll
    for (int ms = 0; ms < 4; ++ms)
      aF[ms] = *(const short8*)(&lA[(wm * 64 + ms * 16 + (lane & 15)) * 40 + ((lane >> 4) << 3)]);
    #pragma unroll
    for (int ns = 0; ns < 4; ++ns)
      bF[ns] = *(const short8*)(&lB[(wn * 64 + ns * 16 + (lane & 15)) * 40 + ((lane >> 4) << 3)]);
    #pragma unroll
    for (int ms = 0; ms < 4; ++ms)
      #pragma unroll
      for (int ns = 0; ns < 4; ++ns)
        acc[ms][ns] = __builtin_amdgcn_mfma_f32_16x16x32_bf16(aF[ms], bF[ns], acc[ms][ns], 0, 0, 0);
  }
  #pragma unroll
  for (int ns = 0; ns < 4; ++ns) {
    const int nn = n0 + wn * 64 + ns * 16 + (lane & 15);
    const float bs = obias[nn];
    #pragma unroll
    for (int ms = 0; ms < 4; ++ms) {
      const int mm = m0 + wm * 64 + ms * 16 + ((lane >> 4) << 2);
      #pragma unroll
      for (int r = 0; r < 4; ++r)
        out[(size_t)(mm + r) * V_ + nn] = acc[ms][ns][r] + bs;
    }
  }
}

// ---- GRU recurrence: 64-WG gang, WG j owns h cols [j*16, j*16+16). Whh B-frags in VGPRs.
// ALL cross-WG traffic = RELAXED agent atomics (sc-flagged, LLC coherence point, no L2 residency).
// NO threadfence / release / acquire: no buffer_wbl2/buffer_inv cache walks. Ordering is
// "atomic stores drained by __syncthreads (s_waitcnt vmcnt(0) before s_barrier) -> relaxed flag".
// h layout in hbuf (qwords): [buf][col4][row16], col4 = global_col/4 -> frag loads coalesce.
__global__ __launch_bounds__(256, 1) void k_gru(const float* __restrict__ xg,
                                                const float* __restrict__ Whh,
                                                const float* __restrict__ bhh,
                                                const float* __restrict__ h0,
                                                unsigned long long* hbuf, int* flags,
                                                float* __restrict__ hn_out,
                                                unsigned short* __restrict__ ys) {
  __shared__ float lred[3072];               // [wave][tau][n][m] partial tiles
  const int tid = threadIdx.x;
  const int lane = tid & 63, wave = tid >> 6;
  const int j = blockIdx.x;
  const int b = tid & 15, c = tid >> 4;      // c = wave*4 + (lane>>4)
  const int hc = j * 16 + c;
  const int kbase = wave * 256;              // each wave covers a K-quarter

  // Whh B-fragments (fp32 -> bf16) into registers, once.
  short8 bfrag[3][8];
  #pragma unroll
  for (int tau = 0; tau < 3; ++tau) {
    const float* wr = Whh + (size_t)(tau * H_ + j * 16 + (lane & 15)) * H_;
    #pragma unroll
    for (int s8 = 0; s8 < 8; ++s8) {
      int k = kbase + s8 * 32 + ((lane >> 4) << 3);
      float4 p0 = *(const float4*)(wr + k);
      float4 p1 = *(const float4*)(wr + k + 4);
      bfrag[tau][s8] = cvt8(p0, p1);
    }
  }
  const float bh0 = bhh[hc], bh1 = bhh[H_ + hc], bh2 = bhh[2 * H_ + hc];
  float h_own = h0 ? h0[b * H_ + hc] : 0.f;

  // Shuffle-pack own column value and store one qword (4 cols x row b) per lane<16.
  // Lane L: col c = wave*4 + (L>>4), row = L&15. xor16 pairs cols, xor32 pairs pairs.
  #define PACK_STORE(HVAL, BUF)                                                              \
    {                                                                                        \
      unsigned wlo = f2bf(HVAL);                                                             \
      unsigned p = wlo | (((unsigned)__shfl_xor((int)wlo, 16, 64)) << 16);                   \
      unsigned long long qv = (unsigned long long)p |                                        \
          (((unsigned long long)(unsigned)__shfl_xor((int)p, 32, 64)) << 32);                \
      if (lane < 16)                                                                         \
        __hip_atomic_store(hbuf + (size_t)(BUF) * 4096 + (j * 4 + wave) * 16 + lane, qv,     \
                           __ATOMIC_RELAXED, __HIP_MEMORY_SCOPE_AGENT);                      \
    }

  PACK_STORE(h_own, 0)
  // gate prefetch for s=0 (independent of the barrier)
  float xr = xg[hc * 16 + b];
  float xz = xg[(H_ + hc) * 16 + b];
  float xn = xg[(2 * H_ + hc) * 16 + b];
  __syncthreads();  // drains the atomic stores (vmcnt(0) before s_barrier)
  if (tid == 0) __hip_atomic_store(flags + j, 1, __ATOMIC_RELAXED, __HIP_MEMORY_SCOPE_AGENT);
  if (wave == 0) {
    for (;;) {
      int f = __hip_atomic_load(flags + lane, __ATOMIC_RELAXED, __HIP_MEMORY_SCOPE_AGENT);
      if (__all(f >= 1)) break;   // poison 0xAAAAAAAA is negative -> safe
      __builtin_amdgcn_s_sleep(1);
    }
  }
  __syncthreads();

  for (int s = 0; s < T_; ++s) {
    // A-fragments straight from LLC into registers (no LDS staging, no extra barrier).
    const unsigned long long* src = hbuf + (size_t)(s & 1) * 4096;
    unsigned long long qa0[8], qa1[8];
    #pragma unroll
    for (int s8 = 0; s8 < 8; ++s8) {
      const int qi = (wave * 64 + s8 * 8 + ((lane >> 4) << 1)) * 16 + (lane & 15);
      qa0[s8] = __hip_atomic_load(src + qi,      __ATOMIC_RELAXED, __HIP_MEMORY_SCOPE_AGENT);
      qa1[s8] = __hip_atomic_load(src + qi + 16, __ATOMIC_RELAXED, __HIP_MEMORY_SCOPE_AGENT);
    }
    floatx4 a0 = {0.f,0.f,0.f,0.f}, a1 = {0.f,0.f,0.f,0.f}, a2 = {0.f,0.f,0.f,0.f};
    #pragma unroll
    for (int s8 = 0; s8 < 8; ++s8) {
      union { unsigned long long q[2]; short8 v; } u;
      u.q[0] = qa0[s8]; u.q[1] = qa1[s8];
      a0 = __builtin_amdgcn_mfma_f32_16x16x32_bf16(u.v, bfrag[0][s8], a0, 0, 0, 0);
      a1 = __builtin_amdgcn_mfma_f32_16x16x32_bf16(u.v, bfrag[1][s8], a1, 0, 0, 0);
      a2 = __builtin_amdgcn_mfma_f32_16x16x32_bf16(u.v, bfrag[2][s8], a2, 0, 0, 0);
    }
    {
      int pb = wave * 768 + (lane & 15) * 16 + ((lane >> 4) << 2);
      *(floatx4*)(&lred[pb])       = a0;
      *(floatx4*)(&lred[pb + 256]) = a1;
      *(floatx4*)(&lred[pb + 512]) = a2;
    }
    __syncthreads();
    float g0 = bh0, g1 = bh1, g2 = bh2;
    #pragma unroll
    for (int wv = 0; wv < 4; ++wv) {
      int rb = wv * 768 + c * 16 + b;
      g0 += lred[rb]; g1 += lred[rb + 256]; g2 += lred[rb + 512];
    }
    const float rg = 1.f / (1.f + expf(-(xr + g0)));
    const float zg = 1.f / (1.f + expf(-(xz + g1)));
    const float ng = tanhf(xn + rg * g2);
    const float hnew = (1.f - zg) * ng + zg * h_own;
    h_own = hnew;
    if (ys) ys[(size_t)(b * T_ + s) * H_ + hc] = f2bf(hnew);
    PACK_STORE(hnew, (s + 1) & 1)
    if (s < T_ - 1) {
      // prefetch next step's gates while waiting
      const float* xgn = xg + (size_t)(s + 1) * (G3_ * 16);
      float xrN = xgn[hc * 16 + b];
      float xzN = xgn[(H_ + hc) * 16 + b];
      float xnN = xgn[(2 * H_ + hc) * 16 + b];
      __syncthreads();  // drains this step's h stores
      if (tid == 0) __hip_atomic_store(flags + j, s + 2, __ATOMIC_RELAXED, __HIP_MEMORY_SCOPE_AGENT);
      if (wave == 0) {
        for (;;) {
          int f = __hip_atomic_load(flags + lane, __ATOMIC_RELAXED, __HIP_MEMORY_SCOPE_AGENT);
          if (__all(f >= s + 2)) break;
          __builtin_amdgcn_s_sleep(1);
        }
      }
      __syncthreads();
      xr = xrN; xz = xzN; xn = xnN;
    }
  }
  if (hn_out) hn_out[b * H_ + hc] = h_own;
  #undef PACK_STORE
}

// ---- VAE heads: mu/logvar/style/content (+ cat buffer for fc). One wave per (b,o). ----
__global__ void k_heads(const float* __restrict__ hn,
                        const float* __restrict__ musW, const float* __restrict__ musb,
                        const float* __restrict__ varsW, const float* __restrict__ varsb,
                        const float* __restrict__ mucW, const float* __restrict__ mucb,
                        const float* __restrict__ varcW, const float* __restrict__ varcb,
                        const float* __restrict__ eps_s, const float* __restrict__ eps_c,
                        float* __restrict__ out, float* __restrict__ cat) {
  const int wv = blockIdx.x * 4 + (threadIdx.x >> 6);
  const int lane = threadIdx.x & 63;
  const int b = wv >> 8, o = wv & 255;
  const float* h = hn + (size_t)b * H_;
  const float *w1, *w2; float bb1, bb2, ep; int oc = 0;
  const int smode = (o < 64);
  if (smode) { w1 = musW + (size_t)o * H_;  w2 = varsW + (size_t)o * H_;  bb1 = musb[o];  bb2 = varsb[o];  ep = eps_s[b * 64 + o]; }
  else { oc = o - 64; w1 = mucW + (size_t)oc * H_; w2 = varcW + (size_t)oc * H_; bb1 = mucb[oc]; bb2 = varcb[oc]; ep = eps_c[b * 192 + oc]; }
  float s1 = 0.f, s2 = 0.f;
  #pragma unroll
  for (int i = 0; i < 4; ++i) {
    int k = lane * 4 + i * 256;
    float4 hv = *(const float4*)(h + k);
    float4 av = *(const float4*)(w1 + k);
    float4 bv = *(const float4*)(w2 + k);
    s1 += dot4(hv, av); s2 += dot4(hv, bv);
  }
  s1 = wsum(s1); s2 = wsum(s2);
  if (lane == 0) {
    const float mu = s1 + bb1, lv = s2 + bb2;
    const float sc = mu + ep * expf(0.5f * lv);
    if (smode) {
      out[OF_MUS + b * 64 + o] = mu;
      out[OF_LVS + b * 64 + o] = lv;
      out[OF_STYLE + b * 64 + o] = sc;
      cat[b * 256 + o] = sc;
    } else {
      out[OF_MUC + b * 192 + oc] = mu;
      out[OF_LVC + b * 192 + oc] = lv;
      out[OF_CONTENT + b * 192 + oc] = sc;
      cat[b * 256 + 64 + oc] = sc;
    }
  }
}

// ---- z = cat @ fc_W^T + fc_b : one wave per (b,h), K=256 = 64 lanes x float4 ----
__global__ void k_z(const float* __restrict__ cat, const float* __restrict__ fcW,
                    const float* __restrict__ fcb, float* __restrict__ z) {
  const int wv = blockIdx.x * 4 + (threadIdx.x >> 6);
  const int lane = threadIdx.x & 63;
  const int b = wv >> 10, h = wv & 1023;
  float4 a = *(const float4*)(cat + b * 256 + lane * 4);
  float4 w = *(const float4*)(fcW + (size_t)h * 256 + lane * 4);
  float p = dot4(a, w);
  p = wsum(p);
  if (lane == 0) z[b * H_ + h] = p + fcb[h];
}

extern "C" void kernel_launch(void* const* d_in, const int* in_sizes, int n_in,
                              void* d_out, int out_size, void* d_ws, size_t ws_size,
                              hipStream_t stream) {
  (void)in_sizes; (void)n_in; (void)out_size;
  const int*   x       = (const int*)d_in[0];
  const int*   sos     = (const int*)d_in[1];
  const float* eps_s   = (const float*)d_in[2];
  const float* eps_c   = (const float*)d_in[3];
  const float* emb     = (const float*)d_in[4];
  const float* ln_g    = (const float*)d_in[5];
  const float* ln_b    = (const float*)d_in[6];
  const float* enc_Wih = (const float*)d_in[7];
  const float* enc_Whh = (const float*)d_in[8];
  const float* enc_bih = (const float*)d_in[9];
  const float* enc_bhh = (const float*)d_in[10];
  const float* mus_W   = (const float*)d_in[11];
  const float* mus_b   = (const float*)d_in[12];
  const float* vars_W  = (const float*)d_in[13];
  const float* vars_b  = (const float*)d_in[14];
  const float* muc_W   = (const float*)d_in[15];
  const float* muc_b   = (const float*)d_in[16];
  const float* varc_W  = (const float*)d_in[17];
  const float* varc_b  = (const float*)d_in[18];
  const float* fc_W    = (const float*)d_in[19];
  const float* fc_b    = (const float*)d_in[20];
  const float* dec_Wih = (const float*)d_in[21];
  const float* dec_Whh = (const float*)d_in[22];
  const float* dec_bih = (const float*)d_in[23];
  const float* dec_bhh = (const float*)d_in[24];
  const float* out_W   = (const float*)d_in[25];
  const float* out_b   = (const float*)d_in[26];
  float* out = (float*)d_out;

  char* w = (char*)d_ws;
  unsigned short* e2   = (unsigned short*)(w + 0);          // 1,310,720
  unsigned short* de2  = (unsigned short*)(w + 1310720);    // 1,310,720
  unsigned short* wihE = (unsigned short*)(w + 2621440);    // 1,966,080
  unsigned short* wihD = (unsigned short*)(w + 4587520);    // 1,966,080
  float* xgE           = (float*)(w + 6553600);             // 25,165,824
  float* xgD           = (float*)(w + 31719424);            // 25,165,824
  unsigned short* ys   = (unsigned short*)(w + 56885248);   // 4,194,304
  unsigned long long* hbuf = (unsigned long long*)(w + 61079552);  // 65,536
  float* hn            = (float*)(w + 61145088);            // 65,536
  float* zb            = (float*)(w + 61210624);            // 65,536
  float* catb          = (float*)(w + 61276160);            // 16,384
  int* flagsE          = (int*)(w + 61292544);              // 256
  int* flagsD          = flagsE + 64;                       // 256
  unsigned short* woutBf = (unsigned short*)(w + 61293056); // 65,536,000 (optional)
  const bool bigws = (ws_size >= 126829056ull);

  k_wih<<<960, 256, 0, stream>>>(enc_Wih, wihE);
  k_wih<<<960, 256, 0, stream>>>(dec_Wih, wihD);
  if (bigws) k_cvtw<<<2048, 256, 0, stream>>>(out_W, woutBf, V_ * H_ / 4);
  k_embed<<<513, 256, 0, stream>>>(x, sos, emb, ln_g, ln_b, e2, de2);
  k_xg<<<384, 256, 0, stream>>>(wihE, e2, enc_bih, xgE);
  k_xg<<<384, 256, 0, stream>>>(wihD, de2, dec_bih, xgD);
  k_gru<<<64, 256, 0, stream>>>(xgE, enc_Whh, enc_bhh, (const float*)nullptr,
                                hbuf, flagsE, hn, (unsigned short*)nullptr);
  k_heads<<<1024, 256, 0, stream>>>(hn, mus_W, mus_b, vars_W, vars_b,
                                    muc_W, muc_b, varc_W, varc_b, eps_s, eps_c, out, catb);
  k_z<<<4096, 256, 0, stream>>>(catb, fc_W, fc_b, zb);
  k_gru<<<64, 256, 0, stream>>>(xgD, dec_Whh, dec_bhh, zb,
                                hbuf, flagsD, (float*)nullptr, ys);
  if (bigws) k_final_bf<<<4000, 256, 0, stream>>>(ys, woutBf, out_b, out);
  else       k_final<<<4000, 256, 0, stream>>>(ys, out_W, out_b, out);
}